// Round 1
// baseline (381.454 us; speedup 1.0000x reference)
//
#include <hip/hip_runtime.h>

typedef __attribute__((ext_vector_type(4))) float f32x4;
typedef __attribute__((ext_vector_type(8))) short s16x8;

#define ADJ_N 8192

__device__ __forceinline__ unsigned short f2bf(float f) {
  unsigned u = __float_as_uint(f);
  u += 0x7FFFu + ((u >> 16) & 1u);
  return (unsigned short)(u >> 16);
}

// ---------------------------------------------------------------------------
// Build B0 = W0 (bf16) in MFMA-fragment layout.
// W0[k=r*8192+m][col] = sum_b c0[r,b]*w0[b,m,col];  layout [ks][cg][lane][8]
// lane holds B[k=ks*32+8*(lane>>4)+j][col=cg*16+(lane&15)]
// ---------------------------------------------------------------------------
__global__ __launch_bounds__(256) void build_B0(
    const float* __restrict__ w0, const float* __restrict__ c0,
    unsigned short* __restrict__ Bsw) {
  const int t = blockIdx.x * 256 + threadIdx.x;   // 0..262143
  const int ks = t >> 9;
  const int cg = (t >> 6) & 7;
  const int lane = t & 63;
  const int kb = ks * 32 + ((lane >> 4) << 3);
  const int col = cg * 16 + (lane & 15);
  const int r = kb >> 13;
  const int m = kb & (ADJ_N - 1);
  const float a0 = c0[r * 2 + 0], a1 = c0[r * 2 + 1];
  union { unsigned short v[8]; s16x8 s; } out;
#pragma unroll
  for (int j = 0; j < 8; ++j) {
    const size_t idx = (size_t)(m + j) * 128 + col;
    const float f = a0 * w0[idx] + a1 * w0[(size_t)1048576 + idx];
    out.v[j] = f2bf(f);
  }
  ((s16x8*)Bsw)[t] = out.s;
}

// ---------------------------------------------------------------------------
// Build B1 = Hc (bf16) in fragment layout: Hc[k=r*8192+m][p] =
//   sum_o relu(out0[m][o]) * (c1[r,0]*w1[0][o][p] + c1[r,1]*w1[1][o][p])
// grid 256 blocks, each handles 32 rows m.
// ---------------------------------------------------------------------------
__global__ __launch_bounds__(256) void build_B1(
    const float* __restrict__ out0, const float* __restrict__ w1,
    const float* __restrict__ c1, unsigned short* __restrict__ Bsw1) {
  __shared__ __align__(16) float hs[32][128];       // 16 KB
  __shared__ __align__(16) float w1t[2][64 * 128];  // 64 KB, [r][p][o] swizzled
  const int tid = threadIdx.x;
  const int m0 = blockIdx.x * 32;

  for (int i = tid; i < 32 * 128; i += 256) {
    hs[i >> 7][i & 127] = fmaxf(out0[(size_t)(m0 + (i >> 7)) * 128 + (i & 127)], 0.f);
  }
  const float ca[2][2] = {{c1[0], c1[1]}, {c1[2], c1[3]}};
  for (int i = tid; i < 2 * 64 * 128; i += 256) {
    const int rr = i >> 13;
    const int p = (i >> 7) & 63;
    const int o = i & 127;
    const float v = ca[rr][0] * w1[(size_t)o * 64 + p] + ca[rr][1] * w1[8192 + (size_t)o * 64 + p];
    const int ch = (o >> 2) ^ (p & 31);             // bank swizzle
    w1t[rr][p * 128 + ch * 4 + (o & 3)] = v;
  }
  __syncthreads();

  for (int idx = tid; idx < 4096; idx += 256) {
    const int p = idx & 63;
    const int ml = (idx >> 6) & 31;
    const int rr = idx >> 11;
    float s = 0.f;
#pragma unroll
    for (int ch = 0; ch < 32; ++ch) {
      const f32x4 hv = *(const f32x4*)&hs[ml][ch * 4];
      const f32x4 wv = *(const f32x4*)((const char*)&w1t[rr][0] +
                                       ((size_t)p * 32 + (ch ^ (p & 31))) * 16);
      s += hv[0] * wv[0] + hv[1] * wv[1] + hv[2] * wv[2] + hv[3] * wv[3];
    }
    const int k = rr * ADJ_N + m0 + ml;
    const int ks = k >> 5, kin = k & 31;
    const int lane = ((kin >> 3) << 4) | (p & 15);
    const int j = kin & 7;
    const int cg = p >> 4;
    Bsw1[(((size_t)ks * 4 + cg) * 64 + lane) * 8 + j] = f2bf(s);
  }
}

// ---------------------------------------------------------------------------
// Main GEMM: out[n][c] += sum_{k in split} adj_as_A[n][k] * B[k][c]
// A = adj (fp32 -> bf16 in-register), K = r*8192+m.
// BM=128, BN=BN, BK=64, KSPLIT=8 -> 512 blocks, 256 threads (4 waves 2x2).
// A staged via global_load_lds (linear LDS dest, XOR-swizzled global source),
// B read as pre-packed fragments straight from L2.
// ---------------------------------------------------------------------------
template <int BN>
__global__ __launch_bounds__(256, 2) void gemm_adj(
    const float* __restrict__ adj, const unsigned short* __restrict__ Bsw,
    float* __restrict__ outp) {
  constexpr int BK = 64;
  constexpr int KRANGE = 2048;
  constexpr int NSTEP = KRANGE / BK;  // 32
  constexpr int CGS = BN / 16;        // col groups
  constexpr int FN = CGS / 2;         // col frags per wave
  __shared__ __align__(16) float As[2][128 * BK];  // 64 KB

  const int bx = blockIdx.x;
  const int mblk = bx >> 3;
  const int split = bx & 7;
  const int n0 = mblk * 128;
  const int k0 = split * KRANGE;
  const int r = k0 >> 13;                 // 2048-aligned: never crosses r
  const int m0 = k0 & (ADJ_N - 1);
  const float* __restrict__ adjr =
      adj + ((size_t)r << 26) + (size_t)n0 * ADJ_N + m0;

  const int tid = threadIdx.x;
  const int w = tid >> 6;
  const int lane = tid & 63;
  const int wm = w >> 1, wn = w & 1;
  const int lhi = lane >> 4;   // 0..3
  const int llo = lane & 15;

  f32x4 acc[4][FN];
#pragma unroll
  for (int a = 0; a < 4; ++a)
#pragma unroll
    for (int b = 0; b < FN; ++b) acc[a][b] = (f32x4){0.f, 0.f, 0.f, 0.f};

  // stage one 128x64 fp32 A tile: wave w covers rows w*32..w*32+31
  // LDS linear: row*256B + chunk'*16B ; global chunk = chunk' ^ (row&15)
  auto stage = [&](int buf, int step) {
    const float* g0 = adjr + step * BK;
#pragma unroll
    for (int i = 0; i < 8; ++i) {
      const int row = w * 32 + i * 4 + lhi;
      const int srcc = llo ^ (row & 15);
      const float* g = g0 + (size_t)row * ADJ_N + srcc * 4;
      __builtin_amdgcn_global_load_lds(
          (const __attribute__((address_space(1))) void*)g,
          (__attribute__((address_space(3))) void*)((char*)&As[buf][0] +
                                                    (w * 32 + i * 4) * 256),
          16, 0, 0);
    }
  };

  stage(0, 0);
  __syncthreads();

  int buf = 0;
  for (int s = 0; s < NSTEP; ++s) {
    if (s + 1 < NSTEP) stage(buf ^ 1, s + 1);
    const int ksbase = (k0 >> 5) + s * 2;
    const char* Ab = (const char*)&As[buf][0];
#pragma unroll
    for (int kc = 0; kc < 2; ++kc) {
      s16x8 afr[4];
#pragma unroll
      for (int fm = 0; fm < 4; ++fm) {
        const int row = wm * 64 + fm * 16 + llo;  // row & 15 == llo
        const int x = kc * 8 + 2 * lhi;
        const f32x4 lo = *(const f32x4*)(Ab + (size_t)row * 256 + ((x ^ llo) * 16));
        const f32x4 hi = *(const f32x4*)(Ab + (size_t)row * 256 + (((x + 1) ^ llo) * 16));
        unsigned u0, u1, u2, u3;
        asm("v_cvt_pk_bf16_f32 %0, %1, %2" : "=v"(u0) : "v"(lo[0]), "v"(lo[1]));
        asm("v_cvt_pk_bf16_f32 %0, %1, %2" : "=v"(u1) : "v"(lo[2]), "v"(lo[3]));
        asm("v_cvt_pk_bf16_f32 %0, %1, %2" : "=v"(u2) : "v"(hi[0]), "v"(hi[1]));
        asm("v_cvt_pk_bf16_f32 %0, %1, %2" : "=v"(u3) : "v"(hi[2]), "v"(hi[3]));
        union { unsigned u[4]; s16x8 v; } cv;
        cv.u[0] = u0; cv.u[1] = u1; cv.u[2] = u2; cv.u[3] = u3;
        afr[fm] = cv.v;
      }
      s16x8 bfr[FN];
#pragma unroll
      for (int fc = 0; fc < FN; ++fc) {
        const int cg = wn * FN + fc;
        bfr[fc] = ((const s16x8*)Bsw)[((size_t)(ksbase + kc) * CGS + cg) * 64 + lane];
      }
#pragma unroll
      for (int fm = 0; fm < 4; ++fm)
#pragma unroll
        for (int fc = 0; fc < FN; ++fc)
          acc[fm][fc] = __builtin_amdgcn_mfma_f32_16x16x32_bf16(
              afr[fm], bfr[fc], acc[fm][fc], 0, 0, 0);
    }
    __syncthreads();
    buf ^= 1;
  }

  // epilogue: C/D layout col=lane&15, row=(lane>>4)*4+q (verified m89/m91)
#pragma unroll
  for (int fm = 0; fm < 4; ++fm)
#pragma unroll
    for (int fc = 0; fc < FN; ++fc)
#pragma unroll
      for (int q = 0; q < 4; ++q) {
        const int rown = n0 + wm * 64 + fm * 16 + lhi * 4 + q;
        const int coln = wn * (FN * 16) + fc * 16 + llo;
        atomicAdd(&outp[(size_t)rown * BN + coln], acc[fm][fc][q]);
      }
}

// ---------------------------------------------------------------------------
// final_rep: frep[j<128] = sum_n out0[n][j]; frep[128+p] = sum_n out1[n][p]
// ---------------------------------------------------------------------------
__global__ __launch_bounds__(256) void finalize_rep(
    const float* __restrict__ out0, const float* __restrict__ out1,
    float* __restrict__ frep) {
  __shared__ float red[256];
  const int t = threadIdx.x;
  const int nbase = blockIdx.x * 128;
  {
    const int col = t & 127, ro = t >> 7;
    float s = 0.f;
    for (int n = ro; n < 128; n += 2) s += out0[(size_t)(nbase + n) * 128 + col];
    red[t] = s;
  }
  __syncthreads();
  if (t < 128) atomicAdd(&frep[t], red[t] + red[t + 128]);
  __syncthreads();
  {
    const int col = t & 63, ro = t >> 6;
    float s = 0.f;
    for (int n = ro; n < 128; n += 4) s += out1[(size_t)(nbase + n) * 64 + col];
    red[t] = s;
  }
  __syncthreads();
  if (t < 64) atomicAdd(&frep[128 + t], red[t] + red[t + 64] + red[t + 128] + red[t + 192]);
}

// ---------------------------------------------------------------------------
extern "C" void kernel_launch(void* const* d_in, const int* in_sizes, int n_in,
                              void* d_out, int out_size, void* d_ws, size_t ws_size,
                              hipStream_t stream) {
  const float* adj = (const float*)d_in[0];
  const float* bw0 = (const float*)d_in[1];
  const float* bc0 = (const float*)d_in[2];
  const float* bw1 = (const float*)d_in[3];
  const float* bc1 = (const float*)d_in[4];
  float* out = (float*)d_out;

  char* ws = (char*)d_ws;
  float* out0 = (float*)ws;                                   // 4 MB fp32
  unsigned short* B0 = (unsigned short*)(ws + (4u << 20));    // 4 MB bf16 frags
  unsigned short* B1 = (unsigned short*)(ws + (8u << 20));    // 2 MB bf16 frags

  hipMemsetAsync(out0, 0, (size_t)8192 * 128 * sizeof(float), stream);
  hipMemsetAsync(d_out, 0, (size_t)out_size * sizeof(float), stream);

  build_B0<<<1024, 256, 0, stream>>>(bw0, bc0, B0);
  gemm_adj<128><<<512, 256, 0, stream>>>(adj, B0, out0);
  build_B1<<<256, 256, 0, stream>>>(out0, bw1, bc1, B1);
  gemm_adj<64><<<512, 256, 0, stream>>>(adj, B1, out);
  finalize_rep<<<64, 256, 0, stream>>>(out0, out, out + (size_t)8192 * 64);
}

// Round 2
// 266.935 us; speedup vs baseline: 1.4290x; 1.4290x over previous
//
#include <hip/hip_runtime.h>

typedef __attribute__((ext_vector_type(4))) float f32x4;
typedef __attribute__((ext_vector_type(8))) short s16x8;

#define ADJ_N 8192

__device__ __forceinline__ unsigned short f2bf(float f) {
  unsigned u = __float_as_uint(f);
  u += 0x7FFFu + ((u >> 16) & 1u);
  return (unsigned short)(u >> 16);
}

// ---------------------------------------------------------------------------
// Build B0 = W0 (bf16) in MFMA-fragment layout [ks][cg][lane][8]:
// lane holds B[k=ks*32+8*(lane>>4)+j][col=cg*16+(lane&15)]
// ---------------------------------------------------------------------------
__global__ __launch_bounds__(256) void build_B0(
    const float* __restrict__ w0, const float* __restrict__ c0,
    unsigned short* __restrict__ Bsw) {
  const int t = blockIdx.x * 256 + threadIdx.x;   // 0..262143
  const int ks = t >> 9;
  const int cg = (t >> 6) & 7;
  const int lane = t & 63;
  const int kb = ks * 32 + ((lane >> 4) << 3);
  const int col = cg * 16 + (lane & 15);
  const int r = kb >> 13;
  const int m = kb & (ADJ_N - 1);
  const float a0 = c0[r * 2 + 0], a1 = c0[r * 2 + 1];
  union { unsigned short v[8]; s16x8 s; } out;
#pragma unroll
  for (int j = 0; j < 8; ++j) {
    const size_t idx = (size_t)(m + j) * 128 + col;
    const float f = a0 * w0[idx] + a1 * w0[(size_t)1048576 + idx];
    out.v[j] = f2bf(f);
  }
  ((s16x8*)Bsw)[t] = out.s;
}

// ---------------------------------------------------------------------------
// build_B1: sum the 8 k-split partials of out0, relu, apply W1, emit bf16
// fragments for gemm2; also accumulate column sums of out0 into frep[0:128].
// 256 blocks x 512 threads, 32 rows each.
// ---------------------------------------------------------------------------
__global__ __launch_bounds__(512) void build_B1(
    const float* __restrict__ p0, const float* __restrict__ w1,
    const float* __restrict__ c1, unsigned short* __restrict__ Bsw1,
    float* __restrict__ frep) {
  __shared__ __align__(16) float hs[32][128];       // 16 KB
  __shared__ __align__(16) float w1t[2][64 * 128];  // 64 KB, [r][p][o] swizzled
  __shared__ float red[512];
  const int tid = threadIdx.x;
  const int m0 = blockIdx.x * 32;

  float cs = 0.f;
  for (int i = tid; i < 32 * 128; i += 512) {
    const int ml = i >> 7, col = i & 127;
    const size_t base = (size_t)(m0 + ml) * 128 + col;
    float s = 0.f;
#pragma unroll
    for (int sp = 0; sp < 8; ++sp) s += p0[(size_t)sp * 1048576 + base];
    cs += s;
    hs[ml][col] = fmaxf(s, 0.f);
  }
  const float ca[2][2] = {{c1[0], c1[1]}, {c1[2], c1[3]}};
  for (int i = tid; i < 2 * 64 * 128; i += 512) {
    const int rr = i >> 13;
    const int p = (i >> 7) & 63;
    const int o = i & 127;
    const float v = ca[rr][0] * w1[(size_t)o * 64 + p] + ca[rr][1] * w1[8192 + (size_t)o * 64 + p];
    const int ch = (o >> 2) ^ (p & 31);             // bank swizzle
    w1t[rr][p * 128 + ch * 4 + (o & 3)] = v;
  }
  red[tid] = cs;
  __syncthreads();
  if (tid < 128)
    atomicAdd(&frep[tid], red[tid] + red[tid + 128] + red[tid + 256] + red[tid + 384]);

  for (int idx = tid; idx < 4096; idx += 512) {
    const int p = idx & 63;
    const int ml = (idx >> 6) & 31;
    const int rr = idx >> 11;
    float s = 0.f;
#pragma unroll
    for (int ch = 0; ch < 32; ++ch) {
      const f32x4 hv = *(const f32x4*)&hs[ml][ch * 4];
      const f32x4 wv = *(const f32x4*)((const char*)&w1t[rr][0] +
                                       ((size_t)p * 32 + (ch ^ (p & 31))) * 16);
      s += hv[0] * wv[0] + hv[1] * wv[1] + hv[2] * wv[2] + hv[3] * wv[3];
    }
    const int k = rr * ADJ_N + m0 + ml;
    const int ks = k >> 5, kin = k & 31;
    const int lane = ((kin >> 3) << 4) | (p & 15);
    const int j = kin & 7;
    const int cg = p >> 4;
    Bsw1[(((size_t)ks * 4 + cg) * 64 + lane) * 8 + j] = f2bf(s);
  }
}

// ---------------------------------------------------------------------------
// Main GEMM: partial[split][n][c] = sum_{k in split} adj[n][k] * B[k][c]
// BM=64, BK=64, KSPLIT=8 -> 1024 blocks, 4 waves, each wave owns a private
// 16-row MFMA tile: A goes global->reg->cvt->MFMA (no A LDS, no A barriers).
// B fragments double-buffered in LDS via global_load_lds (linear, no swizzle).
// REV=true walks K backwards (gemm2 reuses gemm1's L3-resident tail).
// ---------------------------------------------------------------------------
template <int BN, bool REV>
__global__ __launch_bounds__(256, 4) void gemm_adj(
    const float* __restrict__ adj, const unsigned short* __restrict__ Bfr,
    float* __restrict__ outp) {
  constexpr int BK = 64;
  constexpr int KRANGE = 2048;
  constexpr int NSTEP = KRANGE / BK;   // 32
  constexpr int CGS = BN / 16;         // 8 or 4
  __shared__ __align__(16) unsigned short Bsb[2][2 * CGS * 512];  // 2*CGS KB x2

  const int bx = blockIdx.x;
  const int mblk = bx >> 3;            // split = bx&7 -> pinned to XCD bx%8
  const int split = bx & 7;
  const int n0 = mblk * 64;
  const int k0 = split * KRANGE;
  const int r = k0 >> 13;
  const int m0k = k0 & (ADJ_N - 1);

  const int tid = threadIdx.x;
  const int w = tid >> 6;
  const int lane = tid & 63;
  const int lhi = lane >> 4;   // 0..3
  const int llo = lane & 15;

  const float* __restrict__ adjw = adj + ((size_t)r << 26) +
      (size_t)(n0 + w * 16 + llo) * ADJ_N + m0k + lhi * 8;

  f32x4 acc[CGS];
#pragma unroll
  for (int b = 0; b < CGS; ++b) acc[b] = (f32x4){0.f, 0.f, 0.f, 0.f};

  auto loadA = [&](int step, f32x4 (&dst)[4]) {
#pragma unroll
    for (int kc = 0; kc < 2; ++kc)
#pragma unroll
      for (int h = 0; h < 2; ++h)
        dst[kc * 2 + h] = *(const f32x4*)(adjw + step * BK + kc * 32 + h * 4);
  };

  auto stageB = [&](int buf, int step) {
    const int ksb = (k0 >> 5) + step * 2;
    const unsigned short* g = Bfr + (size_t)ksb * CGS * 512 + w * (CGS / 2) * 512 + lane * 8;
#pragma unroll
    for (int i = 0; i < CGS / 2; ++i) {
      __builtin_amdgcn_global_load_lds(
          (const __attribute__((address_space(1))) void*)(g + i * 512),
          (__attribute__((address_space(3))) void*)((char*)&Bsb[buf][0] +
                                                    (w * (CGS / 2) + i) * 1024),
          16, 0, 0);
    }
  };

  auto compute = [&](int buf, f32x4 (&cur)[4]) {
#pragma unroll
    for (int kc = 0; kc < 2; ++kc) {
      union { unsigned u[4]; s16x8 v; } cv;
      asm("v_cvt_pk_bf16_f32 %0, %1, %2" : "=v"(cv.u[0]) : "v"(cur[kc * 2][0]), "v"(cur[kc * 2][1]));
      asm("v_cvt_pk_bf16_f32 %0, %1, %2" : "=v"(cv.u[1]) : "v"(cur[kc * 2][2]), "v"(cur[kc * 2][3]));
      asm("v_cvt_pk_bf16_f32 %0, %1, %2" : "=v"(cv.u[2]) : "v"(cur[kc * 2 + 1][0]), "v"(cur[kc * 2 + 1][1]));
      asm("v_cvt_pk_bf16_f32 %0, %1, %2" : "=v"(cv.u[3]) : "v"(cur[kc * 2 + 1][2]), "v"(cur[kc * 2 + 1][3]));
#pragma unroll
      for (int fc = 0; fc < CGS; ++fc) {
        const s16x8 b = *(const s16x8*)((const char*)&Bsb[buf][0] +
                                        (((kc * CGS + fc) * 64 + lane) << 4));
        acc[fc] = __builtin_amdgcn_mfma_f32_16x16x32_bf16(cv.v, b, acc[fc], 0, 0, 0);
      }
    }
  };

  f32x4 a0[4], a1[4];
  const int step0 = REV ? NSTEP - 1 : 0;
  loadA(step0, a0);
  stageB(0, step0);
  __syncthreads();

  for (int s2 = 0; s2 < NSTEP; s2 += 2) {
    {
      const int sn = REV ? NSTEP - 2 - s2 : s2 + 1;
      stageB(1, sn);
      loadA(sn, a1);
      compute(0, a0);
      __syncthreads();
    }
    {
      const bool more = (s2 + 2 < NSTEP);
      const int sn = REV ? NSTEP - 3 - s2 : s2 + 2;
      if (more) {
        stageB(0, sn);
        loadA(sn, a0);
      }
      compute(1, a1);
      __syncthreads();
    }
  }

  // epilogue: plain stores to this split's partial tile (no atomics).
  // C/D layout: col=lane&15, row=(lane>>4)*4+q
  float* po = outp + ((size_t)split * ADJ_N + (size_t)n0) * BN;
#pragma unroll
  for (int fc = 0; fc < CGS; ++fc)
#pragma unroll
    for (int q = 0; q < 4; ++q)
      po[(size_t)(w * 16 + lhi * 4 + q) * BN + fc * 16 + llo] = acc[fc][q];
}

// ---------------------------------------------------------------------------
// reduce_out1: out1 = sum of 8 partials; also colsum -> frep[128:192].
// 256 blocks x 256 threads, 32 rows each.
// ---------------------------------------------------------------------------
__global__ __launch_bounds__(256) void reduce_out1(
    const float* __restrict__ p1, float* __restrict__ out1,
    float* __restrict__ frep) {
  __shared__ float red[256];
  const int t = threadIdx.x;
  const int col = t & 63, r0 = t >> 6;
  float cs = 0.f;
  for (int k = 0; k < 8; ++k) {
    const size_t row = (size_t)blockIdx.x * 32 + r0 * 8 + k;
    const size_t idx = row * 64 + col;
    float s = 0.f;
#pragma unroll
    for (int sp = 0; sp < 8; ++sp) s += p1[(size_t)sp * 524288 + idx];
    out1[idx] = s;
    cs += s;
  }
  red[t] = cs;
  __syncthreads();
  if (t < 64)
    atomicAdd(&frep[128 + t], red[t] + red[t + 64] + red[t + 128] + red[t + 192]);
}

// ---------------------------------------------------------------------------
extern "C" void kernel_launch(void* const* d_in, const int* in_sizes, int n_in,
                              void* d_out, int out_size, void* d_ws, size_t ws_size,
                              hipStream_t stream) {
  const float* adj = (const float*)d_in[0];
  const float* bw0 = (const float*)d_in[1];
  const float* bc0 = (const float*)d_in[2];
  const float* bw1 = (const float*)d_in[3];
  const float* bc1 = (const float*)d_in[4];
  float* out = (float*)d_out;
  float* frep = out + (size_t)8192 * 64;

  char* ws = (char*)d_ws;
  float* p0 = (float*)ws;                                      // 32 MB
  float* p1 = (float*)(ws + (32u << 20));                      // 16 MB
  unsigned short* B0 = (unsigned short*)(ws + (48u << 20));    // 4 MB
  unsigned short* B1 = (unsigned short*)(ws + (52u << 20));    // 2 MB

  hipMemsetAsync(frep, 0, 192 * sizeof(float), stream);

  build_B0<<<1024, 256, 0, stream>>>(bw0, bc0, B0);
  gemm_adj<128, false><<<1024, 256, 0, stream>>>(adj, B0, p0);
  build_B1<<<256, 512, 0, stream>>>(p0, bw1, bc1, B1, frep);
  gemm_adj<64, true><<<1024, 256, 0, stream>>>(adj, B1, p1);
  reduce_out1<<<256, 256, 0, stream>>>(p1, out, frep);
}